// Round 11
// baseline (417.708 us; speedup 1.0000x reference)
//
#include <hip/hip_runtime.h>
#include <cmath>

typedef __attribute__((ext_vector_type(8))) short short8;
typedef __attribute__((ext_vector_type(8))) unsigned short ushort8_t;
typedef __attribute__((ext_vector_type(8))) _Float16 half8;
typedef __attribute__((ext_vector_type(4))) float f32x4;
typedef unsigned short u16;

__device__ __forceinline__ u16 f2h(float f) {
    _Float16 h = (_Float16)f;
    return __builtin_bit_cast(u16, h);
}
__device__ __forceinline__ float h2f(u16 b) {
    return (float)__builtin_bit_cast(_Float16, b);
}

#define GLD16(g, l)                                                              \
    __builtin_amdgcn_global_load_lds(                                            \
        (const __attribute__((address_space(1))) unsigned int*)(g),              \
        (__attribute__((address_space(3))) unsigned int*)(l), 16, 0, 0)

#define MFMA_F16(a, b, c)                                                        \
    __builtin_amdgcn_mfma_f32_16x16x32_f16(                                      \
        __builtin_bit_cast(half8, (a)), __builtin_bit_cast(half8, (b)), (c), 0, 0, 0)

// all four f32 -> fp16 casts in one launch; grid 7168 (4096 x-blocks + 3072 W)
__global__ __launch_bounds__(256) void to_h_all(
    const float* __restrict__ x, const float* __restrict__ WQ,
    const float* __restrict__ WK, const float* __restrict__ WV,
    u16* __restrict__ xh, u16* __restrict__ Wh)
{
    int bid = blockIdx.x;
    const float* src;
    u16* dst;
    int off;
    if (bid < 4096) { src = x; dst = xh; off = bid; }
    else {
        int j = bid - 4096;
        int wsel = j >> 10;
        off = j & 1023;
        src = wsel == 0 ? WQ : (wsel == 1 ? WK : WV);
        dst = Wh + (size_t)wsel * 1024 * 1024;
    }
    int idx = off * 256 + threadIdx.x;
    float4 v = reinterpret_cast<const float4*>(src)[idx];
    ushort4 h;
    h.x = f2h(v.x); h.y = f2h(v.y); h.z = f2h(v.z); h.w = f2h(v.w);
    reinterpret_cast<ushort4*>(dst)[idx] = h;
}

// ============ m97-style 128x128 GEMM, fp16, K=1024, 32KB LDS ============
// 256 thr = 4 waves (2Mx2N, wave tile 64x64). Single-buffer 2-barrier loop
// -> ~4 blocks/CU co-resident (overlap hides prologue/epilogue/drain).
// MODE 0 (logits): S = A x B'^T with Hamilton perm (sign via Bneg=Khn);
//   epilogue: wave-local LDS transpose, 64-col stats pm/ps, fp16 D store.
// MODE 1 (qkv): C = A x B^T; epilogue by col panel: Qh / Kh+Khn / Vt^T.
template<int MODE, int NCOL>
__global__ __launch_bounds__(256) void gemm128(
    const u16* __restrict__ A, const u16* __restrict__ B, const u16* __restrict__ Bneg,
    u16* __restrict__ out0, float* __restrict__ pm, float* __restrict__ ps,
    u16* __restrict__ Kh, u16* __restrict__ Khn, u16* __restrict__ Vt,
    int perm_packed, int sign_packed)
{
    __shared__ u16 LA[128 * 64];
    __shared__ u16 LB[128 * 64];
    const int tid = threadIdx.x;
    const int l = tid & 63, w = tid >> 6;
    const int wr = w >> 1, wc = w & 1;
    const int lr = l & 15, lh = l >> 4;
    // bijective XCD swizzle; consecutive swz share a row-panel (A L2-reuse)
    const int bid = (int)blockIdx.x;
    const int q = (NCOL * 32) >> 3;
    const int swz = (bid & 7) * q + (bid >> 3);
    const int row0 = (swz / NCOL) * 128, col0 = (swz % NCOL) * 128;
    const int srow = l >> 3;
    const int scol = ((l & 7) ^ (l >> 3)) * 8;

    f32x4 acc[4][4] = {};

    for (int t = 0; t < 16; ++t) {
        int kA = t * 64, kB;
        const u16* Bsrc = B;
        if (MODE == 0) {
            int ch = kA >> 8;
            int p = (perm_packed >> (2 * ch)) & 3;
            if ((sign_packed >> ch) & 1) Bsrc = Bneg;
            kB = (p << 8) + (kA & 255);
        } else {
            kB = kA;
        }
        __syncthreads();   // all waves done reading previous tile
        #pragma unroll
        for (int i = 0; i < 4; ++i) {
            int r0 = (w * 4 + i) * 8;
            GLD16(&A[(size_t)(row0 + r0 + srow) * 1024 + kA + scol], &LA[r0 * 64]);
        }
        #pragma unroll
        for (int i = 0; i < 4; ++i) {
            int r0 = (w * 4 + i) * 8;
            GLD16(&Bsrc[(size_t)(col0 + r0 + srow) * 1024 + kB + scol], &LB[r0 * 64]);
        }
        __syncthreads();   // compiler drains vmcnt before barrier
        #pragma unroll
        for (int kh = 0; kh < 2; ++kh) {
            short8 af[4], bf[4];
            #pragma unroll
            for (int m = 0; m < 4; ++m)
                af[m] = *reinterpret_cast<const short8*>(
                    &LA[(wr * 64 + m * 16 + lr) * 64 + ((kh * 4 + lh) ^ (lr & 7)) * 8]);
            #pragma unroll
            for (int n = 0; n < 4; ++n)
                bf[n] = *reinterpret_cast<const short8*>(
                    &LB[(wc * 64 + n * 16 + lr) * 64 + ((kh * 4 + lh) ^ (lr & 7)) * 8]);
            #pragma unroll
            for (int m = 0; m < 4; ++m)
                #pragma unroll
                for (int n = 0; n < 4; ++n)
                    acc[m][n] = MFMA_F16(af[m], bf[n], acc[m][n]);
        }
    }

    if (MODE == 0) {
        // ---- wave-local LDS-transpose epilogue + 64-col stats + D store ----
        __syncthreads();   // T region spans LA+LB; ensure all reads done
        const int tcol = (col0 >> 6) + wc;
        float* T = reinterpret_cast<float*>(&LA[0]) + w * 1088;   // 16x68 f32
        const int rq = l >> 2;
        const int cq = l & 3;
        #pragma unroll
        for (int m = 0; m < 4; ++m) {
            #pragma unroll
            for (int n = 0; n < 4; ++n)
                #pragma unroll
                for (int j = 0; j < 4; ++j)
                    T[(lh * 4 + j) * 68 + n * 16 + lr] = acc[m][n][j];
            float vals[16];
            #pragma unroll
            for (int qq = 0; qq < 4; ++qq) {
                f32x4 v4 = *reinterpret_cast<const f32x4*>(&T[rq * 68 + cq * 16 + qq * 4]);
                vals[qq * 4 + 0] = v4[0]; vals[qq * 4 + 1] = v4[1];
                vals[qq * 4 + 2] = v4[2]; vals[qq * 4 + 3] = v4[3];
            }
            float mx = vals[0];
            #pragma unroll
            for (int c = 1; c < 16; ++c) mx = fmaxf(mx, vals[c]);
            mx = fmaxf(mx, __shfl_xor(mx, 1, 64));
            mx = fmaxf(mx, __shfl_xor(mx, 2, 64));
            float s = 0.f;
            #pragma unroll
            for (int c = 0; c < 16; ++c) s += expf(vals[c] - mx);
            s += __shfl_xor(s, 1, 64);
            s += __shfl_xor(s, 2, 64);
            int row = row0 + wr * 64 + m * 16 + rq;
            if (cq == 0) {
                pm[(size_t)row * 64 + tcol] = mx;
                ps[(size_t)row * 64 + tcol] = s;
            }
            ushort8_t d0, d1;
            #pragma unroll
            for (int c = 0; c < 8; ++c) d0[c] = f2h(vals[c] - mx);
            #pragma unroll
            for (int c = 0; c < 8; ++c) d1[c] = f2h(vals[c + 8] - mx);
            size_t go = (size_t)row * 4096 + col0 + wc * 64 + cq * 16;
            *reinterpret_cast<ushort8_t*>(&out0[go]) = d0;
            *reinterpret_cast<ushort8_t*>(&out0[go + 8]) = d1;
        }
    } else {
        const int mode = col0 >> 10;   // 0=Q, 1=K, 2=V (uniform per block)
        #pragma unroll
        for (int m = 0; m < 4; ++m)
            #pragma unroll
            for (int n = 0; n < 4; ++n) {
                int gr = row0 + wr * 64 + m * 16 + lh * 4;
                int gc = col0 + wc * 64 + n * 16 + lr;
                int gcl = gc & 1023;
                f32x4 v = acc[m][n];
                if (mode == 0) {
                    #pragma unroll
                    for (int j = 0; j < 4; ++j)
                        out0[(size_t)(gr + j) * 1024 + gcl] = f2h(v[j]);
                } else if (mode == 1) {
                    #pragma unroll
                    for (int j = 0; j < 4; ++j) {
                        u16 h = f2h(v[j]);
                        size_t o = (size_t)(gr + j) * 1024 + gcl;
                        Kh[o] = h; Khn[o] = h ^ 0x8000;
                    }
                } else {
                    ushort4 o;
                    o.x = f2h(v[0]); o.y = f2h(v[1]); o.z = f2h(v[2]); o.w = f2h(v[3]);
                    *reinterpret_cast<ushort4*>(&Vt[(size_t)gcl * 4096 + gr]) = o;
                }
            }
    }
}

// ============ fused softmax + PV, split-K 8, fp16 D-logits ============
template<bool WRITE_W>
__global__ __launch_bounds__(256) void pv_fused(
    const u16* __restrict__ Lh, float* __restrict__ Wout,
    const u16* __restrict__ Vt, const float* __restrict__ pm,
    const float* __restrict__ ps, u16* __restrict__ ypart, int c256)
{
    __shared__ u16 As[64 * 64];
    __shared__ u16 Bs[256 * 64];
    __shared__ float Red[64][4];
    __shared__ float Ms[64], Is[64];
    const int tid = threadIdx.x;
    const int l = tid & 63, w = tid >> 6;
    const int lr = l & 15, lh = l >> 4;
    const int kc = blockIdx.x;
    const int row0 = blockIdx.y * 64;
    const int kbase = kc * 512;
    const int srow = l >> 3, scol = ((l & 7) ^ (l >> 3)) * 8;

    {
        int row = tid & 63, part = tid >> 6;
        const float* pmr = &pm[(size_t)(row0 + row) * 64 + part * 16];
        const float* psr = &ps[(size_t)(row0 + row) * 64 + part * 16];
        float M = -INFINITY;
        #pragma unroll
        for (int i = 0; i < 16; ++i) M = fmaxf(M, pmr[i]);
        Red[row][part] = M;
        __syncthreads();
        float Mg = fmaxf(fmaxf(Red[row][0], Red[row][1]),
                         fmaxf(Red[row][2], Red[row][3]));
        float S = 0.f;
        #pragma unroll
        for (int i = 0; i < 16; ++i) S += psr[i] * expf(pmr[i] - Mg);
        __syncthreads();
        Red[row][part] = S;
        __syncthreads();
        if (tid < 64) {
            float Sg = Red[tid][0] + Red[tid][1] + Red[tid][2] + Red[tid][3];
            Ms[tid] = Mg;
            Is[tid] = 1.0f / Sg;
        }
        __syncthreads();
    }

    float Mr[4], Ir[4];
    #pragma unroll
    for (int i = 0; i < 4; ++i) { int r = (tid >> 4) + i * 16; Mr[i] = Ms[r]; Ir[i] = Is[r]; }

    f32x4 acc[4][4] = {};

    for (int kt = 0; kt < 8; ++kt) {
        const int tcol = kc * 8 + kt;
        __syncthreads();
        #pragma unroll
        for (int i = 0; i < 4; ++i) {
            int idx = tid + i * 256;
            int r = idx >> 4, s4 = idx & 15;
            float coff = pm[(size_t)(row0 + r) * 64 + tcol] - Mr[i];
            size_t ga = (size_t)(row0 + r) * 4096 + kbase + kt * 64 + s4 * 4;
            ushort4 dv = *reinterpret_cast<const ushort4*>(&Lh[ga]);
            float e0 = expf(h2f(dv.x) + coff) * Ir[i];
            float e1 = expf(h2f(dv.y) + coff) * Ir[i];
            float e2 = expf(h2f(dv.z) + coff) * Ir[i];
            float e3 = expf(h2f(dv.w) + coff) * Ir[i];
            if (WRITE_W)
                *reinterpret_cast<float4*>(&Wout[ga]) = make_float4(e0, e1, e2, e3);
            ushort4 h;
            h.x = f2h(e0); h.y = f2h(e1); h.z = f2h(e2); h.w = f2h(e3);
            int dst = ((s4 >> 1) ^ (r & 7)) * 8 + (s4 & 1) * 4;
            *reinterpret_cast<ushort4*>(&As[r * 64 + dst]) = h;
        }
        #pragma unroll
        for (int i = 0; i < 8; ++i) {
            int r0 = w * 64 + i * 8;
            GLD16(&Vt[(size_t)(c256 + r0 + srow) * 4096 + kbase + kt * 64 + scol],
                  &Bs[r0 * 64]);
        }
        __syncthreads();
        #pragma unroll
        for (int kh = 0; kh < 2; ++kh) {
            short8 af[4], bfv[4];
            #pragma unroll
            for (int m = 0; m < 4; ++m)
                af[m] = *reinterpret_cast<const short8*>(
                    &As[(m * 16 + lr) * 64 + ((kh * 4 + lh) ^ (lr & 7)) * 8]);
            #pragma unroll
            for (int n = 0; n < 4; ++n)
                bfv[n] = *reinterpret_cast<const short8*>(
                    &Bs[(w * 64 + n * 16 + lr) * 64 + ((kh * 4 + lh) ^ (lr & 7)) * 8]);
            #pragma unroll
            for (int m = 0; m < 4; ++m)
                #pragma unroll
                for (int n = 0; n < 4; ++n)
                    acc[m][n] = MFMA_F16(af[m], bfv[n], acc[m][n]);
        }
    }

    #pragma unroll
    for (int m = 0; m < 4; ++m)
        #pragma unroll
        for (int n = 0; n < 4; ++n) {
            int rr = m * 16 + lh * 4;
            int col = w * 64 + n * 16 + lr;
            #pragma unroll
            for (int j = 0; j < 4; ++j)
                ypart[((size_t)kc * 4096 + row0 + rr + j) * 256 + col] = f2h(acc[m][n][j]);
        }
}

// y[:, c256..c256+256] = sum over 8 k-chunk fp16 partials (f32 accumulate)
__global__ __launch_bounds__(256) void reduce_y(const u16* __restrict__ ypart,
                                                float* __restrict__ y, int c256)
{
    int idx = blockIdx.x * 256 + threadIdx.x;
    int r = idx >> 6, c4 = (idx & 63) * 4;
    float s0 = 0.f, s1 = 0.f, s2 = 0.f, s3 = 0.f;
    #pragma unroll
    for (int kc = 0; kc < 8; ++kc) {
        ushort4 p = *reinterpret_cast<const ushort4*>(
            &ypart[((size_t)kc * 4096 + r) * 256 + c4]);
        s0 += h2f(p.x); s1 += h2f(p.y); s2 += h2f(p.z); s3 += h2f(p.w);
    }
    *reinterpret_cast<float4*>(&y[(size_t)r * 1024 + c256 + c4]) =
        make_float4(s0, s1, s2, s3);
}

extern "C" void kernel_launch(void* const* d_in, const int* in_sizes, int n_in,
                              void* d_out, int out_size, void* d_ws, size_t ws_size,
                              hipStream_t stream)
{
    const int n = 4096, d = 1024;
    const float* x  = (const float*)d_in[0];
    const float* WQ = (const float*)d_in[1];
    const float* WK = (const float*)d_in[2];
    const float* WV = (const float*)d_in[3];

    float* y = (float*)d_out;                  // [4096,1024]
    float* wout = y + (size_t)n * d;           // [4096,4096] final w (c=3 only)

    // ws layout. xh/Wh alias the Lh region (consumed by qkv before logits
    // first writes Lh — stream-ordered).
    u16* Lh   = (u16*)d_ws;                    // [4096][4096] fp16 D  (33.5 MB)
    u16* xh   = Lh;                            // [4096,1024] fp16 (alias)
    u16* Wh   = Lh + (size_t)n * 1024;         // [3072,1024] fp16 (alias)
    u16* Qh   = Lh + (size_t)n * 4096;         // [4096,1024] fp16
    u16* Kh   = Qh  + (size_t)n * 1024;
    u16* Khn  = Kh  + (size_t)n * 1024;
    u16* Vt   = Khn + (size_t)n * 1024;        // [1024,4096] fp16 V^T
    u16* ypart = Vt + (size_t)d * 4096;        // [8][4096][256] fp16 (16 MB)
    float* pm = (float*)(ypart + (size_t)8 * n * 256);   // [4096][64]
    float* ps = pm + (size_t)n * 64;           // [4096][64]
    // total ws ~83.5 MB

    to_h_all<<<7168, 256, 0, stream>>>(x, WQ, WK, WV, xh, Wh);

    // QKV: [4096,3072] x [3072,1024]^T in 128^2 tiles, grid 32x24=768
    gemm128<1, 24><<<768, 256, 0, stream>>>(
        xh, Wh, nullptr, Qh, nullptr, nullptr, Kh, Khn, Vt, 0, 0);

    const int permv[4] = {0xE4, 0xB1, 0x4E, 0x1B};
    const int signv[4] = {0x0E, 0x08, 0x02, 0x04};

    for (int c = 0; c < 4; ++c) {
        gemm128<0, 32><<<1024, 256, 0, stream>>>(
            Qh, Kh, Khn, Lh, pm, ps, nullptr, nullptr, nullptr, permv[c], signv[c]);
        if (c == 3)
            pv_fused<true><<<dim3(8, 64), 256, 0, stream>>>(Lh, wout, Vt, pm, ps, ypart, c * 256);
        else
            pv_fused<false><<<dim3(8, 64), 256, 0, stream>>>(Lh, wout, Vt, pm, ps, ypart, c * 256);
        reduce_y<<<1024, 256, 0, stream>>>(ypart, y, c * 256);
    }
}

// Round 12
// 333.729 us; speedup vs baseline: 1.2516x; 1.2516x over previous
//
#include <hip/hip_runtime.h>
#include <cmath>

typedef __attribute__((ext_vector_type(8))) short short8;
typedef __attribute__((ext_vector_type(8))) unsigned short ushort8_t;
typedef __attribute__((ext_vector_type(8))) _Float16 half8;
typedef __attribute__((ext_vector_type(4))) float f32x4;
typedef unsigned short u16;

__device__ __forceinline__ u16 f2h(float f) {
    _Float16 h = (_Float16)f;
    return __builtin_bit_cast(u16, h);
}
__device__ __forceinline__ float h2f(u16 b) {
    return (float)__builtin_bit_cast(_Float16, b);
}

#define GLD16(g, l)                                                              \
    __builtin_amdgcn_global_load_lds(                                            \
        (const __attribute__((address_space(1))) unsigned int*)(g),              \
        (__attribute__((address_space(3))) unsigned int*)(l), 16, 0, 0)

#define MFMA_F16(a, b, c)                                                        \
    __builtin_amdgcn_mfma_f32_16x16x32_f16(                                      \
        __builtin_bit_cast(half8, (a)), __builtin_bit_cast(half8, (b)), (c), 0, 0, 0)
#define SBAR() asm volatile("s_barrier" ::: "memory")

// all four f32 -> fp16 casts in one launch; grid 7168 (4096 x-blocks + 3072 W)
__global__ __launch_bounds__(256) void to_h_all(
    const float* __restrict__ x, const float* __restrict__ WQ,
    const float* __restrict__ WK, const float* __restrict__ WV,
    u16* __restrict__ xh, u16* __restrict__ Wh)
{
    int bid = blockIdx.x;
    const float* src;
    u16* dst;
    int off;
    if (bid < 4096) { src = x; dst = xh; off = bid; }
    else {
        int j = bid - 4096;
        int wsel = j >> 10;
        off = j & 1023;
        src = wsel == 0 ? WQ : (wsel == 1 ? WK : WV);
        dst = Wh + (size_t)wsel * 1024 * 1024;
    }
    int idx = off * 256 + threadIdx.x;
    float4 v = reinterpret_cast<const float4*>(src)[idx];
    ushort4 h;
    h.x = f2h(v.x); h.y = f2h(v.y); h.z = f2h(v.z); h.w = f2h(v.w);
    reinterpret_cast<ushort4*>(dst)[idx] = h;
}

// ============ 256x256 8-phase logits kernel, fp16, K=1024 ============
// S = Qh x Kh'^T (Hamilton perm on Kh cols; sign via pre-negated Khn).
// Epilogue: wave-local LDS transpose (no barriers), per-64-col stats
// pm/ps[row*64+tcol], coalesced fp16 store of p = exp(S - rowmax_tile).
__global__ __launch_bounds__(512, 2) void logits8(
    const u16* __restrict__ A, const u16* __restrict__ B, const u16* __restrict__ Bneg,
    u16* __restrict__ P, float* __restrict__ pm, float* __restrict__ ps,
    int perm_packed, int sign_packed)
{
    constexpr int NT = 16;
    __shared__ u16 L[2][2][256 * 64];
    const int tid = threadIdx.x;
    const int l = tid & 63, w = tid >> 6;
    const int wr = w >> 2, wc = w & 3;
    const int lr = l & 15, lh = l >> 4;
    const int bid = (int)blockIdx.x;
    const int swz = (bid & 7) * 32 + (bid >> 3);
    const int row0 = (swz >> 4) * 256, col0 = (swz & 15) * 256;
    const int srow = l >> 3;
    const int scol = ((l & 7) ^ (l >> 3)) * 8;

    f32x4 acc[8][4] = {};

    auto stage = [&](int t) {
        int kA = t * 64;
        int ch = kA >> 8;
        int p = (perm_packed >> (2 * ch)) & 3;
        const u16* Bsrc = ((sign_packed >> ch) & 1) ? Bneg : B;
        int kB = (p << 8) + (kA & 255);
        int bf = t & 1;
        #pragma unroll
        for (int i = 0; i < 4; ++i) {
            int r0 = w * 32 + i * 8;
            GLD16(&A[(size_t)(row0 + r0 + srow) * 1024 + kA + scol], &L[bf][0][r0 * 64]);
        }
        #pragma unroll
        for (int i = 0; i < 4; ++i) {
            int r0 = w * 32 + i * 8;
            GLD16(&Bsrc[(size_t)(col0 + r0 + srow) * 1024 + kB + scol], &L[bf][1][r0 * 64]);
        }
    };
    auto readA = [&](int bf, int m, int kh) -> short8 {
        int row = wr * 128 + m * 16 + lr;
        int c = ((kh * 4 + lh) ^ (lr & 7)) * 8;
        return *reinterpret_cast<const short8*>(&L[bf][0][row * 64 + c]);
    };
    auto readB = [&](int bf, int n, int kh) -> short8 {
        int row = wc * 64 + n * 16 + lr;
        int c = ((kh * 4 + lh) ^ (lr & 7)) * 8;
        return *reinterpret_cast<const short8*>(&L[bf][1][row * 64 + c]);
    };

    stage(0);
    stage(1);
    asm volatile("s_waitcnt vmcnt(8)" ::: "memory");
    SBAR();

    #pragma unroll 2
    for (int t = 0; t < NT; ++t) {
        const int bf = t & 1;
        short8 am[4][2], bn[4][2];
        #pragma unroll
        for (int m = 0; m < 4; ++m) { am[m][0] = readA(bf, m, 0); am[m][1] = readA(bf, m, 1); }
        #pragma unroll
        for (int n = 0; n < 2; ++n) { bn[n][0] = readB(bf, n, 0); bn[n][1] = readB(bf, n, 1); }
        SBAR();
        __builtin_amdgcn_s_setprio(1);
        #pragma unroll
        for (int m = 0; m < 4; ++m)
            #pragma unroll
            for (int n = 0; n < 2; ++n) {
                acc[m][n] = MFMA_F16(am[m][0], bn[n][0], acc[m][n]);
                acc[m][n] = MFMA_F16(am[m][1], bn[n][1], acc[m][n]);
            }
        __builtin_amdgcn_s_setprio(0);
        SBAR();
        #pragma unroll
        for (int n = 2; n < 4; ++n) { bn[n][0] = readB(bf, n, 0); bn[n][1] = readB(bf, n, 1); }
        SBAR();
        __builtin_amdgcn_s_setprio(1);
        #pragma unroll
        for (int m = 0; m < 4; ++m)
            #pragma unroll
            for (int n = 2; n < 4; ++n) {
                acc[m][n] = MFMA_F16(am[m][0], bn[n][0], acc[m][n]);
                acc[m][n] = MFMA_F16(am[m][1], bn[n][1], acc[m][n]);
            }
        __builtin_amdgcn_s_setprio(0);
        SBAR();
        #pragma unroll
        for (int m = 0; m < 4; ++m) { am[m][0] = readA(bf, 4 + m, 0); am[m][1] = readA(bf, 4 + m, 1); }
        SBAR();
        __builtin_amdgcn_s_setprio(1);
        #pragma unroll
        for (int m = 0; m < 4; ++m)
            #pragma unroll
            for (int n = 2; n < 4; ++n) {
                acc[4 + m][n] = MFMA_F16(am[m][0], bn[n][0], acc[4 + m][n]);
                acc[4 + m][n] = MFMA_F16(am[m][1], bn[n][1], acc[4 + m][n]);
            }
        __builtin_amdgcn_s_setprio(0);
        SBAR();
        if (t + 2 < NT) stage(t + 2);
        SBAR();
        __builtin_amdgcn_s_setprio(1);
        #pragma unroll
        for (int m = 0; m < 4; ++m)
            #pragma unroll
            for (int n = 0; n < 2; ++n) {
                acc[4 + m][n] = MFMA_F16(am[m][0], bn[n][0], acc[4 + m][n]);
                acc[4 + m][n] = MFMA_F16(am[m][1], bn[n][1], acc[4 + m][n]);
            }
        __builtin_amdgcn_s_setprio(0);
        if (t + 2 < NT) { asm volatile("s_waitcnt vmcnt(8)" ::: "memory"); }
        else           { asm volatile("s_waitcnt vmcnt(0)" ::: "memory"); }
        SBAR();
    }

    // ---- wave-local LDS-transpose epilogue (no cross-wave sync needed:
    // all waves passed the loop's final SBAR; each wave uses a private
    // 16x68 f32 region; pitch 68 keeps LDS aliasing at free 2-way). ----
    const int tcol = (col0 >> 6) + wc;
    float* T = reinterpret_cast<float*>(&L[0][0][0]) + w * 1088;   // 16*68 f32
    const int rq = l >> 2;          // row within 16-row m-group
    const int cq = l & 3;           // 16-col quarter
    #pragma unroll
    for (int m = 0; m < 8; ++m) {
        #pragma unroll
        for (int n = 0; n < 4; ++n)
            #pragma unroll
            for (int j = 0; j < 4; ++j)
                T[(lh * 4 + j) * 68 + n * 16 + lr] = acc[m][n][j];
        float vals[16];
        #pragma unroll
        for (int q = 0; q < 4; ++q) {
            f32x4 v4 = *reinterpret_cast<const f32x4*>(&T[rq * 68 + cq * 16 + q * 4]);
            vals[q * 4 + 0] = v4[0]; vals[q * 4 + 1] = v4[1];
            vals[q * 4 + 2] = v4[2]; vals[q * 4 + 3] = v4[3];
        }
        float mx = vals[0];
        #pragma unroll
        for (int c = 1; c < 16; ++c) mx = fmaxf(mx, vals[c]);
        mx = fmaxf(mx, __shfl_xor(mx, 1, 64));
        mx = fmaxf(mx, __shfl_xor(mx, 2, 64));
        float e[16];
        float s = 0.f;
        #pragma unroll
        for (int c = 0; c < 16; ++c) { e[c] = expf(vals[c] - mx); s += e[c]; }
        s += __shfl_xor(s, 1, 64);
        s += __shfl_xor(s, 2, 64);
        int row = row0 + wr * 128 + m * 16 + rq;
        if (cq == 0) {
            pm[(size_t)row * 64 + tcol] = mx;
            ps[(size_t)row * 64 + tcol] = s;
        }
        ushort8_t d0, d1;
        #pragma unroll
        for (int c = 0; c < 8; ++c) d0[c] = f2h(e[c]);
        #pragma unroll
        for (int c = 0; c < 8; ++c) d1[c] = f2h(e[c + 8]);
        size_t go = (size_t)row * 4096 + col0 + wc * 64 + cq * 16;
        *reinterpret_cast<ushort8_t*>(&P[go]) = d0;
        *reinterpret_cast<ushort8_t*>(&P[go + 8]) = d1;
    }
}

// ============ fused QKV projection, 8-phase 256x256, fp16 K=1024 ============
__global__ __launch_bounds__(512, 2) void qkv8(
    const u16* __restrict__ A, const u16* __restrict__ B,
    u16* __restrict__ Qh, u16* __restrict__ Kh, u16* __restrict__ Khn,
    u16* __restrict__ Vt)
{
    constexpr int NT = 16;
    __shared__ u16 L[2][2][256 * 64];
    const int tid = threadIdx.x;
    const int l = tid & 63, w = tid >> 6;
    const int wr = w >> 2, wc = w & 3;
    const int lr = l & 15, lh = l >> 4;
    const int bid = (int)blockIdx.x;
    const int wgid = (bid & 7) * 24 + (bid >> 3);
    const int row0 = (wgid / 12) * 256, col0 = (wgid % 12) * 256;
    const int srow = l >> 3;
    const int scol = ((l & 7) ^ (l >> 3)) * 8;

    f32x4 acc[8][4] = {};

    auto stage = [&](int t) {
        int k0 = t * 64;
        int bf = t & 1;
        #pragma unroll
        for (int i = 0; i < 4; ++i) {
            int r0 = w * 32 + i * 8;
            GLD16(&A[(size_t)(row0 + r0 + srow) * 1024 + k0 + scol], &L[bf][0][r0 * 64]);
        }
        #pragma unroll
        for (int i = 0; i < 4; ++i) {
            int r0 = w * 32 + i * 8;
            GLD16(&B[(size_t)(col0 + r0 + srow) * 1024 + k0 + scol], &L[bf][1][r0 * 64]);
        }
    };
    auto readA = [&](int bf, int m, int kh) -> short8 {
        int row = wr * 128 + m * 16 + lr;
        int c = ((kh * 4 + lh) ^ (lr & 7)) * 8;
        return *reinterpret_cast<const short8*>(&L[bf][0][row * 64 + c]);
    };
    auto readB = [&](int bf, int n, int kh) -> short8 {
        int row = wc * 64 + n * 16 + lr;
        int c = ((kh * 4 + lh) ^ (lr & 7)) * 8;
        return *reinterpret_cast<const short8*>(&L[bf][1][row * 64 + c]);
    };

    stage(0);
    stage(1);
    asm volatile("s_waitcnt vmcnt(8)" ::: "memory");
    SBAR();

    #pragma unroll 2
    for (int t = 0; t < NT; ++t) {
        const int bf = t & 1;
        short8 am[4][2], bn[4][2];
        #pragma unroll
        for (int m = 0; m < 4; ++m) { am[m][0] = readA(bf, m, 0); am[m][1] = readA(bf, m, 1); }
        #pragma unroll
        for (int n = 0; n < 2; ++n) { bn[n][0] = readB(bf, n, 0); bn[n][1] = readB(bf, n, 1); }
        SBAR();
        __builtin_amdgcn_s_setprio(1);
        #pragma unroll
        for (int m = 0; m < 4; ++m)
            #pragma unroll
            for (int n = 0; n < 2; ++n) {
                acc[m][n] = MFMA_F16(am[m][0], bn[n][0], acc[m][n]);
                acc[m][n] = MFMA_F16(am[m][1], bn[n][1], acc[m][n]);
            }
        __builtin_amdgcn_s_setprio(0);
        SBAR();
        #pragma unroll
        for (int n = 2; n < 4; ++n) { bn[n][0] = readB(bf, n, 0); bn[n][1] = readB(bf, n, 1); }
        SBAR();
        __builtin_amdgcn_s_setprio(1);
        #pragma unroll
        for (int m = 0; m < 4; ++m)
            #pragma unroll
            for (int n = 2; n < 4; ++n) {
                acc[m][n] = MFMA_F16(am[m][0], bn[n][0], acc[m][n]);
                acc[m][n] = MFMA_F16(am[m][1], bn[n][1], acc[m][n]);
            }
        __builtin_amdgcn_s_setprio(0);
        SBAR();
        #pragma unroll
        for (int m = 0; m < 4; ++m) { am[m][0] = readA(bf, 4 + m, 0); am[m][1] = readA(bf, 4 + m, 1); }
        SBAR();
        __builtin_amdgcn_s_setprio(1);
        #pragma unroll
        for (int m = 0; m < 4; ++m)
            #pragma unroll
            for (int n = 2; n < 4; ++n) {
                acc[4 + m][n] = MFMA_F16(am[m][0], bn[n][0], acc[4 + m][n]);
                acc[4 + m][n] = MFMA_F16(am[m][1], bn[n][1], acc[4 + m][n]);
            }
        __builtin_amdgcn_s_setprio(0);
        SBAR();
        if (t + 2 < NT) stage(t + 2);
        SBAR();
        __builtin_amdgcn_s_setprio(1);
        #pragma unroll
        for (int m = 0; m < 4; ++m)
            #pragma unroll
            for (int n = 0; n < 2; ++n) {
                acc[4 + m][n] = MFMA_F16(am[m][0], bn[n][0], acc[4 + m][n]);
                acc[4 + m][n] = MFMA_F16(am[m][1], bn[n][1], acc[4 + m][n]);
            }
        __builtin_amdgcn_s_setprio(0);
        if (t + 2 < NT) { asm volatile("s_waitcnt vmcnt(8)" ::: "memory"); }
        else           { asm volatile("s_waitcnt vmcnt(0)" ::: "memory"); }
        SBAR();
    }

    const int mode = col0 >> 10;   // 0=Q, 1=K, 2=V (uniform per block)
    #pragma unroll
    for (int m = 0; m < 8; ++m)
        #pragma unroll
        for (int n = 0; n < 4; ++n) {
            int gr = row0 + wr * 128 + m * 16 + lh * 4;
            int gc = col0 + wc * 64 + n * 16 + lr;
            int gcl = gc & 1023;
            f32x4 v = acc[m][n];
            if (mode == 0) {
                #pragma unroll
                for (int j = 0; j < 4; ++j)
                    Qh[(size_t)(gr + j) * 1024 + gcl] = f2h(v[j]);
            } else if (mode == 1) {
                #pragma unroll
                for (int j = 0; j < 4; ++j) {
                    u16 h = f2h(v[j]);
                    size_t o = (size_t)(gr + j) * 1024 + gcl;
                    Kh[o] = h; Khn[o] = h ^ 0x8000;
                }
            } else {
                ushort4 o;
                o.x = f2h(v[0]); o.y = f2h(v[1]); o.z = f2h(v[2]); o.w = f2h(v[3]);
                *reinterpret_cast<ushort4*>(&Vt[(size_t)gcl * 4096 + gr]) = o;
            }
        }
}

// ============ fused softmax + PV, split-K 8, fp16 p input ============
// Reads p = fp16 exp(l - m_tile); w = p * alpha, alpha = exp(m_t - M)/S
// (one expf per row-tile). fp16 MFMA vs Vt; fp16 y-partials.
template<bool WRITE_W>
__global__ __launch_bounds__(256) void pv_fused(
    const u16* __restrict__ P, float* __restrict__ Wout,
    const u16* __restrict__ Vt, const float* __restrict__ pm,
    const float* __restrict__ ps, u16* __restrict__ ypart, int c256)
{
    __shared__ u16 As[64 * 64];
    __shared__ u16 Bs[256 * 64];
    __shared__ float Red[64][4];
    __shared__ float Ms[64], Is[64];
    const int tid = threadIdx.x;
    const int l = tid & 63, w = tid >> 6;
    const int lr = l & 15, lh = l >> 4;
    const int kc = blockIdx.x;
    const int row0 = blockIdx.y * 64;
    const int kbase = kc * 512;
    const int srow = l >> 3, scol = ((l & 7) ^ (l >> 3)) * 8;

    {
        int row = tid & 63, part = tid >> 6;
        const float* pmr = &pm[(size_t)(row0 + row) * 64 + part * 16];
        const float* psr = &ps[(size_t)(row0 + row) * 64 + part * 16];
        float M = -INFINITY;
        #pragma unroll
        for (int i = 0; i < 16; ++i) M = fmaxf(M, pmr[i]);
        Red[row][part] = M;
        __syncthreads();
        float Mg = fmaxf(fmaxf(Red[row][0], Red[row][1]),
                         fmaxf(Red[row][2], Red[row][3]));
        float S = 0.f;
        #pragma unroll
        for (int i = 0; i < 16; ++i) S += psr[i] * expf(pmr[i] - Mg);
        __syncthreads();
        Red[row][part] = S;
        __syncthreads();
        if (tid < 64) {
            float Sg = Red[tid][0] + Red[tid][1] + Red[tid][2] + Red[tid][3];
            Ms[tid] = Mg;
            Is[tid] = 1.0f / Sg;
        }
        __syncthreads();
    }

    float Mr[4], Ir[4];
    #pragma unroll
    for (int i = 0; i < 4; ++i) { int r = (tid >> 4) + i * 16; Mr[i] = Ms[r]; Ir[i] = Is[r]; }

    f32x4 acc[4][4] = {};

    for (int kt = 0; kt < 8; ++kt) {
        const int tcol = kc * 8 + kt;
        __syncthreads();
        // stage A: w = p * alpha -> fp16, XOR-swizzled write
        #pragma unroll
        for (int i = 0; i < 4; ++i) {
            int idx = tid + i * 256;
            int r = idx >> 4, s4 = idx & 15;
            float alpha = expf(pm[(size_t)(row0 + r) * 64 + tcol] - Mr[i]) * Ir[i];
            size_t ga = (size_t)(row0 + r) * 4096 + kbase + kt * 64 + s4 * 4;
            ushort4 dv = *reinterpret_cast<const ushort4*>(&P[ga]);
            float e0 = h2f(dv.x) * alpha;
            float e1 = h2f(dv.y) * alpha;
            float e2 = h2f(dv.z) * alpha;
            float e3 = h2f(dv.w) * alpha;
            if (WRITE_W)
                *reinterpret_cast<float4*>(&Wout[ga]) = make_float4(e0, e1, e2, e3);
            ushort4 h;
            h.x = f2h(e0); h.y = f2h(e1); h.z = f2h(e2); h.w = f2h(e3);
            int dst = ((s4 >> 1) ^ (r & 7)) * 8 + (s4 & 1) * 4;
            *reinterpret_cast<ushort4*>(&As[r * 64 + dst]) = h;
        }
        #pragma unroll
        for (int i = 0; i < 8; ++i) {
            int r0 = w * 64 + i * 8;
            GLD16(&Vt[(size_t)(c256 + r0 + srow) * 4096 + kbase + kt * 64 + scol],
                  &Bs[r0 * 64]);
        }
        __syncthreads();
        #pragma unroll
        for (int kh = 0; kh < 2; ++kh) {
            short8 af[4], bfv[4];
            #pragma unroll
            for (int m = 0; m < 4; ++m)
                af[m] = *reinterpret_cast<const short8*>(
                    &As[(m * 16 + lr) * 64 + ((kh * 4 + lh) ^ (lr & 7)) * 8]);
            #pragma unroll
            for (int n = 0; n < 4; ++n)
                bfv[n] = *reinterpret_cast<const short8*>(
                    &Bs[(w * 64 + n * 16 + lr) * 64 + ((kh * 4 + lh) ^ (lr & 7)) * 8]);
            #pragma unroll
            for (int m = 0; m < 4; ++m)
                #pragma unroll
                for (int n = 0; n < 4; ++n)
                    acc[m][n] = MFMA_F16(af[m], bfv[n], acc[m][n]);
        }
    }

    #pragma unroll
    for (int m = 0; m < 4; ++m)
        #pragma unroll
        for (int n = 0; n < 4; ++n) {
            int rr = m * 16 + lh * 4;
            int col = w * 64 + n * 16 + lr;
            #pragma unroll
            for (int j = 0; j < 4; ++j)
                ypart[((size_t)kc * 4096 + row0 + rr + j) * 256 + col] = f2h(acc[m][n][j]);
        }
}

// y[:, c256..c256+256] = sum over 8 k-chunk fp16 partials (f32 accumulate)
__global__ __launch_bounds__(256) void reduce_y(const u16* __restrict__ ypart,
                                                float* __restrict__ y, int c256)
{
    int idx = blockIdx.x * 256 + threadIdx.x;
    int r = idx >> 6, c4 = (idx & 63) * 4;
    float s0 = 0.f, s1 = 0.f, s2 = 0.f, s3 = 0.f;
    #pragma unroll
    for (int kc = 0; kc < 8; ++kc) {
        ushort4 p = *reinterpret_cast<const ushort4*>(
            &ypart[((size_t)kc * 4096 + r) * 256 + c4]);
        s0 += h2f(p.x); s1 += h2f(p.y); s2 += h2f(p.z); s3 += h2f(p.w);
    }
    *reinterpret_cast<float4*>(&y[(size_t)r * 1024 + c256 + c4]) =
        make_float4(s0, s1, s2, s3);
}

extern "C" void kernel_launch(void* const* d_in, const int* in_sizes, int n_in,
                              void* d_out, int out_size, void* d_ws, size_t ws_size,
                              hipStream_t stream)
{
    const int n = 4096, d = 1024;
    const float* x  = (const float*)d_in[0];
    const float* WQ = (const float*)d_in[1];
    const float* WK = (const float*)d_in[2];
    const float* WV = (const float*)d_in[3];

    float* y = (float*)d_out;                  // [4096,1024]
    float* wout = y + (size_t)n * d;           // [4096,4096] final w (c=3 only)

    // ws layout. xh/Wh alias the P region (consumed by qkv8 before logits8
    // first writes P — stream-ordered).
    u16* P    = (u16*)d_ws;                    // [4096][4096] fp16 p  (33.5 MB)
    u16* xh   = P;                             // [4096,1024] fp16 (alias)
    u16* Wh   = P + (size_t)n * 1024;          // [3072,1024] fp16 (alias)
    u16* Qh   = P + (size_t)n * 4096;          // [4096,1024] fp16
    u16* Kh   = Qh  + (size_t)n * 1024;
    u16* Khn  = Kh  + (size_t)n * 1024;
    u16* Vt   = Khn + (size_t)n * 1024;        // [1024,4096] fp16 V^T
    u16* ypart = Vt + (size_t)d * 4096;        // [8][4096][256] fp16 (16 MB)
    float* pm = (float*)(ypart + (size_t)8 * n * 256);   // [4096][64]
    float* ps = pm + (size_t)n * 64;           // [4096][64]
    // total ws ~83.5 MB

    to_h_all<<<7168, 256, 0, stream>>>(x, WQ, WK, WV, xh, Wh);

    qkv8<<<192, 512, 0, stream>>>(xh, Wh, Qh, Kh, Khn, Vt);

    const int permv[4] = {0xE4, 0xB1, 0x4E, 0x1B};
    const int signv[4] = {0x0E, 0x08, 0x02, 0x04};

    for (int c = 0; c < 4; ++c) {
        logits8<<<256, 512, 0, stream>>>(Qh, Kh, Khn, P, pm, ps, permv[c], signv[c]);
        if (c == 3)
            pv_fused<true><<<dim3(8, 64), 256, 0, stream>>>(P, wout, Vt, pm, ps, ypart, c * 256);
        else
            pv_fused<false><<<dim3(8, 64), 256, 0, stream>>>(P, wout, Vt, pm, ps, ypart, c * 256);
        reduce_y<<<1024, 256, 0, stream>>>(ypart, y, c * 256);
    }
}

// Round 13
// 332.202 us; speedup vs baseline: 1.2574x; 1.0046x over previous
//
#include <hip/hip_runtime.h>
#include <cmath>

typedef __attribute__((ext_vector_type(8))) short short8;
typedef __attribute__((ext_vector_type(8))) unsigned short ushort8_t;
typedef __attribute__((ext_vector_type(8))) _Float16 half8;
typedef __attribute__((ext_vector_type(4))) float f32x4;
typedef unsigned short u16;

__device__ __forceinline__ u16 f2h(float f) {
    _Float16 h = (_Float16)f;
    return __builtin_bit_cast(u16, h);
}
__device__ __forceinline__ float h2f(u16 b) {
    return (float)__builtin_bit_cast(_Float16, b);
}

#define GLD16(g, l)                                                              \
    __builtin_amdgcn_global_load_lds(                                            \
        (const __attribute__((address_space(1))) unsigned int*)(g),              \
        (__attribute__((address_space(3))) unsigned int*)(l), 16, 0, 0)

#define MFMA_F16(a, b, c)                                                        \
    __builtin_amdgcn_mfma_f32_16x16x32_f16(                                      \
        __builtin_bit_cast(half8, (a)), __builtin_bit_cast(half8, (b)), (c), 0, 0, 0)
#define SBAR() asm volatile("s_barrier" ::: "memory")

// all four f32 -> fp16 casts in one launch; grid 7168 (4096 x-blocks + 3072 W)
__global__ __launch_bounds__(256) void to_h_all(
    const float* __restrict__ x, const float* __restrict__ WQ,
    const float* __restrict__ WK, const float* __restrict__ WV,
    u16* __restrict__ xh, u16* __restrict__ Wh)
{
    int bid = blockIdx.x;
    const float* src;
    u16* dst;
    int off;
    if (bid < 4096) { src = x; dst = xh; off = bid; }
    else {
        int j = bid - 4096;
        int wsel = j >> 10;
        off = j & 1023;
        src = wsel == 0 ? WQ : (wsel == 1 ? WK : WV);
        dst = Wh + (size_t)wsel * 1024 * 1024;
    }
    int idx = off * 256 + threadIdx.x;
    float4 v = reinterpret_cast<const float4*>(src)[idx];
    ushort4 h;
    h.x = f2h(v.x); h.y = f2h(v.y); h.z = f2h(v.z); h.w = f2h(v.w);
    reinterpret_cast<ushort4*>(dst)[idx] = h;
}

// ============ 256x256 8-phase logits kernel, fp16, K=1024 ============
// S = Qh x Kh'^T (Hamilton perm on Kh cols; sign via pre-negated Khn).
// Epilogue: wave-local LDS transpose (no barriers), per-64-col stats
// pm/ps[row*64+tcol], coalesced fp16 store of p = exp(S - rowmax_tile).
// XCD super-tile swizzle: each XCD owns a 4-row x 8-col panel region
// (32 blocks = 32 CUs) -> per-XCD L2 working set ~6 MB (vs 9.4 before).
__global__ __launch_bounds__(512, 2) void logits8(
    const u16* __restrict__ A, const u16* __restrict__ B, const u16* __restrict__ Bneg,
    u16* __restrict__ P, float* __restrict__ pm, float* __restrict__ ps,
    int perm_packed, int sign_packed)
{
    constexpr int NT = 16;
    __shared__ u16 L[2][2][256 * 64];
    const int tid = threadIdx.x;
    const int l = tid & 63, w = tid >> 6;
    const int wr = w >> 2, wc = w & 3;
    const int lr = l & 15, lh = l >> 4;
    const int bid = (int)blockIdx.x;
    const int xcd = bid & 7, idx = bid >> 3;
    const int rowp = (xcd >> 1) * 4 + (idx >> 3);   // 4-row band per xcd-pair
    const int colp = (xcd & 1) * 8 + (idx & 7);     // 8-col half
    const int row0 = rowp * 256, col0 = colp * 256;
    const int srow = l >> 3;
    const int scol = ((l & 7) ^ (l >> 3)) * 8;

    f32x4 acc[8][4] = {};

    auto stage = [&](int t) {
        int kA = t * 64;
        int ch = kA >> 8;
        int p = (perm_packed >> (2 * ch)) & 3;
        const u16* Bsrc = ((sign_packed >> ch) & 1) ? Bneg : B;
        int kB = (p << 8) + (kA & 255);
        int bf = t & 1;
        #pragma unroll
        for (int i = 0; i < 4; ++i) {
            int r0 = w * 32 + i * 8;
            GLD16(&A[(size_t)(row0 + r0 + srow) * 1024 + kA + scol], &L[bf][0][r0 * 64]);
        }
        #pragma unroll
        for (int i = 0; i < 4; ++i) {
            int r0 = w * 32 + i * 8;
            GLD16(&Bsrc[(size_t)(col0 + r0 + srow) * 1024 + kB + scol], &L[bf][1][r0 * 64]);
        }
    };
    auto readA = [&](int bf, int m, int kh) -> short8 {
        int row = wr * 128 + m * 16 + lr;
        int c = ((kh * 4 + lh) ^ (lr & 7)) * 8;
        return *reinterpret_cast<const short8*>(&L[bf][0][row * 64 + c]);
    };
    auto readB = [&](int bf, int n, int kh) -> short8 {
        int row = wc * 64 + n * 16 + lr;
        int c = ((kh * 4 + lh) ^ (lr & 7)) * 8;
        return *reinterpret_cast<const short8*>(&L[bf][1][row * 64 + c]);
    };

    stage(0);
    stage(1);
    asm volatile("s_waitcnt vmcnt(8)" ::: "memory");
    SBAR();

    #pragma unroll 2
    for (int t = 0; t < NT; ++t) {
        const int bf = t & 1;
        short8 am[4][2], bn[4][2];
        #pragma unroll
        for (int m = 0; m < 4; ++m) { am[m][0] = readA(bf, m, 0); am[m][1] = readA(bf, m, 1); }
        #pragma unroll
        for (int n = 0; n < 2; ++n) { bn[n][0] = readB(bf, n, 0); bn[n][1] = readB(bf, n, 1); }
        SBAR();
        __builtin_amdgcn_s_setprio(1);
        #pragma unroll
        for (int m = 0; m < 4; ++m)
            #pragma unroll
            for (int n = 0; n < 2; ++n) {
                acc[m][n] = MFMA_F16(am[m][0], bn[n][0], acc[m][n]);
                acc[m][n] = MFMA_F16(am[m][1], bn[n][1], acc[m][n]);
            }
        __builtin_amdgcn_s_setprio(0);
        SBAR();
        #pragma unroll
        for (int n = 2; n < 4; ++n) { bn[n][0] = readB(bf, n, 0); bn[n][1] = readB(bf, n, 1); }
        SBAR();
        __builtin_amdgcn_s_setprio(1);
        #pragma unroll
        for (int m = 0; m < 4; ++m)
            #pragma unroll
            for (int n = 2; n < 4; ++n) {
                acc[m][n] = MFMA_F16(am[m][0], bn[n][0], acc[m][n]);
                acc[m][n] = MFMA_F16(am[m][1], bn[n][1], acc[m][n]);
            }
        __builtin_amdgcn_s_setprio(0);
        SBAR();
        #pragma unroll
        for (int m = 0; m < 4; ++m) { am[m][0] = readA(bf, 4 + m, 0); am[m][1] = readA(bf, 4 + m, 1); }
        SBAR();
        __builtin_amdgcn_s_setprio(1);
        #pragma unroll
        for (int m = 0; m < 4; ++m)
            #pragma unroll
            for (int n = 2; n < 4; ++n) {
                acc[4 + m][n] = MFMA_F16(am[m][0], bn[n][0], acc[4 + m][n]);
                acc[4 + m][n] = MFMA_F16(am[m][1], bn[n][1], acc[4 + m][n]);
            }
        __builtin_amdgcn_s_setprio(0);
        SBAR();
        if (t + 2 < NT) stage(t + 2);
        SBAR();
        __builtin_amdgcn_s_setprio(1);
        #pragma unroll
        for (int m = 0; m < 4; ++m)
            #pragma unroll
            for (int n = 0; n < 2; ++n) {
                acc[4 + m][n] = MFMA_F16(am[m][0], bn[n][0], acc[4 + m][n]);
                acc[4 + m][n] = MFMA_F16(am[m][1], bn[n][1], acc[4 + m][n]);
            }
        __builtin_amdgcn_s_setprio(0);
        if (t + 2 < NT) { asm volatile("s_waitcnt vmcnt(8)" ::: "memory"); }
        else           { asm volatile("s_waitcnt vmcnt(0)" ::: "memory"); }
        SBAR();
    }

    // ---- wave-local LDS-transpose epilogue (no cross-wave sync needed) ----
    const int tcol = (col0 >> 6) + wc;
    float* T = reinterpret_cast<float*>(&L[0][0][0]) + w * 1088;   // 16*68 f32
    const int rq = l >> 2;
    const int cq = l & 3;
    #pragma unroll
    for (int m = 0; m < 8; ++m) {
        #pragma unroll
        for (int n = 0; n < 4; ++n)
            #pragma unroll
            for (int j = 0; j < 4; ++j)
                T[(lh * 4 + j) * 68 + n * 16 + lr] = acc[m][n][j];
        float vals[16];
        #pragma unroll
        for (int q = 0; q < 4; ++q) {
            f32x4 v4 = *reinterpret_cast<const f32x4*>(&T[rq * 68 + cq * 16 + q * 4]);
            vals[q * 4 + 0] = v4[0]; vals[q * 4 + 1] = v4[1];
            vals[q * 4 + 2] = v4[2]; vals[q * 4 + 3] = v4[3];
        }
        float mx = vals[0];
        #pragma unroll
        for (int c = 1; c < 16; ++c) mx = fmaxf(mx, vals[c]);
        mx = fmaxf(mx, __shfl_xor(mx, 1, 64));
        mx = fmaxf(mx, __shfl_xor(mx, 2, 64));
        float e[16];
        float s = 0.f;
        #pragma unroll
        for (int c = 0; c < 16; ++c) { e[c] = expf(vals[c] - mx); s += e[c]; }
        s += __shfl_xor(s, 1, 64);
        s += __shfl_xor(s, 2, 64);
        int row = row0 + wr * 128 + m * 16 + rq;
        if (cq == 0) {
            pm[(size_t)row * 64 + tcol] = mx;
            ps[(size_t)row * 64 + tcol] = s;
        }
        ushort8_t d0, d1;
        #pragma unroll
        for (int c = 0; c < 8; ++c) d0[c] = f2h(e[c]);
        #pragma unroll
        for (int c = 0; c < 8; ++c) d1[c] = f2h(e[c + 8]);
        size_t go = (size_t)row * 4096 + col0 + wc * 64 + cq * 16;
        *reinterpret_cast<ushort8_t*>(&P[go]) = d0;
        *reinterpret_cast<ushort8_t*>(&P[go + 8]) = d1;
    }
}

// ============ fused QKV projection, 8-phase 256x256, fp16 K=1024 ============
__global__ __launch_bounds__(512, 2) void qkv8(
    const u16* __restrict__ A, const u16* __restrict__ B,
    u16* __restrict__ Qh, u16* __restrict__ Kh, u16* __restrict__ Khn,
    u16* __restrict__ Vt)
{
    constexpr int NT = 16;
    __shared__ u16 L[2][2][256 * 64];
    const int tid = threadIdx.x;
    const int l = tid & 63, w = tid >> 6;
    const int wr = w >> 2, wc = w & 3;
    const int lr = l & 15, lh = l >> 4;
    const int bid = (int)blockIdx.x;
    const int wgid = (bid & 7) * 24 + (bid >> 3);
    const int row0 = (wgid / 12) * 256, col0 = (wgid % 12) * 256;
    const int srow = l >> 3;
    const int scol = ((l & 7) ^ (l >> 3)) * 8;

    f32x4 acc[8][4] = {};

    auto stage = [&](int t) {
        int k0 = t * 64;
        int bf = t & 1;
        #pragma unroll
        for (int i = 0; i < 4; ++i) {
            int r0 = w * 32 + i * 8;
            GLD16(&A[(size_t)(row0 + r0 + srow) * 1024 + k0 + scol], &L[bf][0][r0 * 64]);
        }
        #pragma unroll
        for (int i = 0; i < 4; ++i) {
            int r0 = w * 32 + i * 8;
            GLD16(&B[(size_t)(col0 + r0 + srow) * 1024 + k0 + scol], &L[bf][1][r0 * 64]);
        }
    };
    auto readA = [&](int bf, int m, int kh) -> short8 {
        int row = wr * 128 + m * 16 + lr;
        int c = ((kh * 4 + lh) ^ (lr & 7)) * 8;
        return *reinterpret_cast<const short8*>(&L[bf][0][row * 64 + c]);
    };
    auto readB = [&](int bf, int n, int kh) -> short8 {
        int row = wc * 64 + n * 16 + lr;
        int c = ((kh * 4 + lh) ^ (lr & 7)) * 8;
        return *reinterpret_cast<const short8*>(&L[bf][1][row * 64 + c]);
    };

    stage(0);
    stage(1);
    asm volatile("s_waitcnt vmcnt(8)" ::: "memory");
    SBAR();

    #pragma unroll 2
    for (int t = 0; t < NT; ++t) {
        const int bf = t & 1;
        short8 am[4][2], bn[4][2];
        #pragma unroll
        for (int m = 0; m < 4; ++m) { am[m][0] = readA(bf, m, 0); am[m][1] = readA(bf, m, 1); }
        #pragma unroll
        for (int n = 0; n < 2; ++n) { bn[n][0] = readB(bf, n, 0); bn[n][1] = readB(bf, n, 1); }
        SBAR();
        __builtin_amdgcn_s_setprio(1);
        #pragma unroll
        for (int m = 0; m < 4; ++m)
            #pragma unroll
            for (int n = 0; n < 2; ++n) {
                acc[m][n] = MFMA_F16(am[m][0], bn[n][0], acc[m][n]);
                acc[m][n] = MFMA_F16(am[m][1], bn[n][1], acc[m][n]);
            }
        __builtin_amdgcn_s_setprio(0);
        SBAR();
        #pragma unroll
        for (int n = 2; n < 4; ++n) { bn[n][0] = readB(bf, n, 0); bn[n][1] = readB(bf, n, 1); }
        SBAR();
        __builtin_amdgcn_s_setprio(1);
        #pragma unroll
        for (int m = 0; m < 4; ++m)
            #pragma unroll
            for (int n = 2; n < 4; ++n) {
                acc[m][n] = MFMA_F16(am[m][0], bn[n][0], acc[m][n]);
                acc[m][n] = MFMA_F16(am[m][1], bn[n][1], acc[m][n]);
            }
        __builtin_amdgcn_s_setprio(0);
        SBAR();
        #pragma unroll
        for (int m = 0; m < 4; ++m) { am[m][0] = readA(bf, 4 + m, 0); am[m][1] = readA(bf, 4 + m, 1); }
        SBAR();
        __builtin_amdgcn_s_setprio(1);
        #pragma unroll
        for (int m = 0; m < 4; ++m)
            #pragma unroll
            for (int n = 2; n < 4; ++n) {
                acc[4 + m][n] = MFMA_F16(am[m][0], bn[n][0], acc[4 + m][n]);
                acc[4 + m][n] = MFMA_F16(am[m][1], bn[n][1], acc[4 + m][n]);
            }
        __builtin_amdgcn_s_setprio(0);
        SBAR();
        if (t + 2 < NT) stage(t + 2);
        SBAR();
        __builtin_amdgcn_s_setprio(1);
        #pragma unroll
        for (int m = 0; m < 4; ++m)
            #pragma unroll
            for (int n = 0; n < 2; ++n) {
                acc[4 + m][n] = MFMA_F16(am[m][0], bn[n][0], acc[4 + m][n]);
                acc[4 + m][n] = MFMA_F16(am[m][1], bn[n][1], acc[4 + m][n]);
            }
        __builtin_amdgcn_s_setprio(0);
        if (t + 2 < NT) { asm volatile("s_waitcnt vmcnt(8)" ::: "memory"); }
        else           { asm volatile("s_waitcnt vmcnt(0)" ::: "memory"); }
        SBAR();
    }

    const int mode = col0 >> 10;   // 0=Q, 1=K, 2=V (uniform per block)
    #pragma unroll
    for (int m = 0; m < 8; ++m)
        #pragma unroll
        for (int n = 0; n < 4; ++n) {
            int gr = row0 + wr * 128 + m * 16 + lh * 4;
            int gc = col0 + wc * 64 + n * 16 + lr;
            int gcl = gc & 1023;
            f32x4 v = acc[m][n];
            if (mode == 0) {
                #pragma unroll
                for (int j = 0; j < 4; ++j)
                    Qh[(size_t)(gr + j) * 1024 + gcl] = f2h(v[j]);
            } else if (mode == 1) {
                #pragma unroll
                for (int j = 0; j < 4; ++j) {
                    u16 h = f2h(v[j]);
                    size_t o = (size_t)(gr + j) * 1024 + gcl;
                    Kh[o] = h; Khn[o] = h ^ 0x8000;
                }
            } else {
                ushort4 o;
                o.x = f2h(v[0]); o.y = f2h(v[1]); o.z = f2h(v[2]); o.w = f2h(v[3]);
                *reinterpret_cast<ushort4*>(&Vt[(size_t)gcl * 4096 + gr]) = o;
            }
        }
}

// ============ fused softmax + PV, split-K 8, fp16 p input ============
template<bool WRITE_W>
__global__ __launch_bounds__(256) void pv_fused(
    const u16* __restrict__ P, float* __restrict__ Wout,
    const u16* __restrict__ Vt, const float* __restrict__ pm,
    const float* __restrict__ ps, u16* __restrict__ ypart, int c256)
{
    __shared__ u16 As[64 * 64];
    __shared__ u16 Bs[256 * 64];
    __shared__ float Red[64][4];
    __shared__ float Ms[64], Is[64];
    const int tid = threadIdx.x;
    const int l = tid & 63, w = tid >> 6;
    const int lr = l & 15, lh = l >> 4;
    const int kc = blockIdx.x;
    const int row0 = blockIdx.y * 64;
    const int kbase = kc * 512;
    const int srow = l >> 3, scol = ((l & 7) ^ (l >> 3)) * 8;

    {
        int row = tid & 63, part = tid >> 6;
        const float* pmr = &pm[(size_t)(row0 + row) * 64 + part * 16];
        const float* psr = &ps[(size_t)(row0 + row) * 64 + part * 16];
        float M = -INFINITY;
        #pragma unroll
        for (int i = 0; i < 16; ++i) M = fmaxf(M, pmr[i]);
        Red[row][part] = M;
        __syncthreads();
        float Mg = fmaxf(fmaxf(Red[row][0], Red[row][1]),
                         fmaxf(Red[row][2], Red[row][3]));
        float S = 0.f;
        #pragma unroll
        for (int i = 0; i < 16; ++i) S += psr[i] * expf(pmr[i] - Mg);
        __syncthreads();
        Red[row][part] = S;
        __syncthreads();
        if (tid < 64) {
            float Sg = Red[tid][0] + Red[tid][1] + Red[tid][2] + Red[tid][3];
            Ms[tid] = Mg;
            Is[tid] = 1.0f / Sg;
        }
        __syncthreads();
    }

    float Mr[4], Ir[4];
    #pragma unroll
    for (int i = 0; i < 4; ++i) { int r = (tid >> 4) + i * 16; Mr[i] = Ms[r]; Ir[i] = Is[r]; }

    f32x4 acc[4][4] = {};

    for (int kt = 0; kt < 8; ++kt) {
        const int tcol = kc * 8 + kt;
        __syncthreads();
        // stage A: w = p * alpha -> fp16, XOR-swizzled write
        #pragma unroll
        for (int i = 0; i < 4; ++i) {
            int idx = tid + i * 256;
            int r = idx >> 4, s4 = idx & 15;
            float alpha = expf(pm[(size_t)(row0 + r) * 64 + tcol] - Mr[i]) * Ir[i];
            size_t ga = (size_t)(row0 + r) * 4096 + kbase + kt * 64 + s4 * 4;
            ushort4 dv = *reinterpret_cast<const ushort4*>(&P[ga]);
            float e0 = h2f(dv.x) * alpha;
            float e1 = h2f(dv.y) * alpha;
            float e2 = h2f(dv.z) * alpha;
            float e3 = h2f(dv.w) * alpha;
            if (WRITE_W)
                *reinterpret_cast<float4*>(&Wout[ga]) = make_float4(e0, e1, e2, e3);
            ushort4 h;
            h.x = f2h(e0); h.y = f2h(e1); h.z = f2h(e2); h.w = f2h(e3);
            int dst = ((s4 >> 1) ^ (r & 7)) * 8 + (s4 & 1) * 4;
            *reinterpret_cast<ushort4*>(&As[r * 64 + dst]) = h;
        }
        #pragma unroll
        for (int i = 0; i < 8; ++i) {
            int r0 = w * 64 + i * 8;
            GLD16(&Vt[(size_t)(c256 + r0 + srow) * 4096 + kbase + kt * 64 + scol],
                  &Bs[r0 * 64]);
        }
        __syncthreads();
        #pragma unroll
        for (int kh = 0; kh < 2; ++kh) {
            short8 af[4], bfv[4];
            #pragma unroll
            for (int m = 0; m < 4; ++m)
                af[m] = *reinterpret_cast<const short8*>(
                    &As[(m * 16 + lr) * 64 + ((kh * 4 + lh) ^ (lr & 7)) * 8]);
            #pragma unroll
            for (int n = 0; n < 4; ++n)
                bfv[n] = *reinterpret_cast<const short8*>(
                    &Bs[(w * 64 + n * 16 + lr) * 64 + ((kh * 4 + lh) ^ (lr & 7)) * 8]);
            #pragma unroll
            for (int m = 0; m < 4; ++m)
                #pragma unroll
                for (int n = 0; n < 4; ++n)
                    acc[m][n] = MFMA_F16(af[m], bfv[n], acc[m][n]);
        }
    }

    #pragma unroll
    for (int m = 0; m < 4; ++m)
        #pragma unroll
        for (int n = 0; n < 4; ++n) {
            int rr = m * 16 + lh * 4;
            int col = w * 64 + n * 16 + lr;
            #pragma unroll
            for (int j = 0; j < 4; ++j)
                ypart[((size_t)kc * 4096 + row0 + rr + j) * 256 + col] = f2h(acc[m][n][j]);
        }
}

// y[:, c256..c256+256] = sum over 8 k-chunk fp16 partials (f32 accumulate)
__global__ __launch_bounds__(256) void reduce_y(const u16* __restrict__ ypart,
                                                float* __restrict__ y, int c256)
{
    int idx = blockIdx.x * 256 + threadIdx.x;
    int r = idx >> 6, c4 = (idx & 63) * 4;
    float s0 = 0.f, s1 = 0.f, s2 = 0.f, s3 = 0.f;
    #pragma unroll
    for (int kc = 0; kc < 8; ++kc) {
        ushort4 p = *reinterpret_cast<const ushort4*>(
            &ypart[((size_t)kc * 4096 + r) * 256 + c4]);
        s0 += h2f(p.x); s1 += h2f(p.y); s2 += h2f(p.z); s3 += h2f(p.w);
    }
    *reinterpret_cast<float4*>(&y[(size_t)r * 1024 + c256 + c4]) =
        make_float4(s0, s1, s2, s3);
}

extern "C" void kernel_launch(void* const* d_in, const int* in_sizes, int n_in,
                              void* d_out, int out_size, void* d_ws, size_t ws_size,
                              hipStream_t stream)
{
    const int n = 4096, d = 1024;
    const float* x  = (const float*)d_in[0];
    const float* WQ = (const float*)d_in[1];
    const float* WK = (const float*)d_in[2];
    const float* WV = (const float*)d_in[3];

    float* y = (float*)d_out;                  // [4096,1024]
    float* wout = y + (size_t)n * d;           // [4096,4096] final w (c=3 only)

    // ws layout. xh/Wh alias the P region (consumed by qkv8 before logits8
    // first writes P — stream-ordered).
    u16* P    = (u16*)d_ws;                    // [4096][4096] fp16 p  (33.5 MB)
    u16* xh   = P;                             // [4096,1024] fp16 (alias)
    u16* Wh   = P + (size_t)n * 1024;          // [3072,1024] fp16 (alias)
    u16* Qh   = P + (size_t)n * 4096;          // [4096,1024] fp16
    u16* Kh   = Qh  + (size_t)n * 1024;
    u16* Khn  = Kh  + (size_t)n * 1024;
    u16* Vt   = Khn + (size_t)n * 1024;        // [1024,4096] fp16 V^T
    u16* ypart = Vt + (size_t)d * 4096;        // [8][4096][256] fp16 (16 MB)
    float* pm = (float*)(ypart + (size_t)8 * n * 256);   // [4096][64]
    float* ps = pm + (size_t)n * 64;           // [4096][64]
    // total ws ~83.5 MB

    to_h_all<<<7168, 256, 0, stream>>>(x, WQ, WK, WV, xh, Wh);

    qkv8<<<192, 512, 0, stream>>>(xh, Wh, Qh, Kh, Khn, Vt);

    const int permv[4] = {0xE4, 0xB1, 0x4E, 0x1B};
    const int signv[4] = {0x0E, 0x08, 0x02, 0x04};

    for (int c = 0; c < 4; ++c) {
        logits8<<<256, 512, 0, stream>>>(Qh, Kh, Khn, P, pm, ps, permv[c], signv[c]);
        if (c == 3)
            pv_fused<true><<<dim3(8, 64), 256, 0, stream>>>(P, wout, Vt, pm, ps, ypart, c * 256);
        else
            pv_fused<false><<<dim3(8, 64), 256, 0, stream>>>(P, wout, Vt, pm, ps, ypart, c * 256);
        reduce_y<<<1024, 256, 0, stream>>>(ypart, y, c * 256);
    }
}

// Round 14
// 330.325 us; speedup vs baseline: 1.2645x; 1.0057x over previous
//
#include <hip/hip_runtime.h>
#include <cmath>

typedef __attribute__((ext_vector_type(8))) short short8;
typedef __attribute__((ext_vector_type(8))) unsigned short ushort8_t;
typedef __attribute__((ext_vector_type(8))) _Float16 half8;
typedef __attribute__((ext_vector_type(4))) float f32x4;
typedef unsigned short u16;

__device__ __forceinline__ u16 f2h(float f) {
    _Float16 h = (_Float16)f;
    return __builtin_bit_cast(u16, h);
}
__device__ __forceinline__ float h2f(u16 b) {
    return (float)__builtin_bit_cast(_Float16, b);
}

#define GLD16(g, l)                                                              \
    __builtin_amdgcn_global_load_lds(                                            \
        (const __attribute__((address_space(1))) unsigned int*)(g),              \
        (__attribute__((address_space(3))) unsigned int*)(l), 16, 0, 0)

#define MFMA_F16(a, b, c)                                                        \
    __builtin_amdgcn_mfma_f32_16x16x32_f16(                                      \
        __builtin_bit_cast(half8, (a)), __builtin_bit_cast(half8, (b)), (c), 0, 0, 0)
#define SBAR() asm volatile("s_barrier" ::: "memory")

// all four f32 -> fp16 casts in one launch; grid 7168 (4096 x-blocks + 3072 W)
__global__ __launch_bounds__(256) void to_h_all(
    const float* __restrict__ x, const float* __restrict__ WQ,
    const float* __restrict__ WK, const float* __restrict__ WV,
    u16* __restrict__ xh, u16* __restrict__ Wh)
{
    int bid = blockIdx.x;
    const float* src;
    u16* dst;
    int off;
    if (bid < 4096) { src = x; dst = xh; off = bid; }
    else {
        int j = bid - 4096;
        int wsel = j >> 10;
        off = j & 1023;
        src = wsel == 0 ? WQ : (wsel == 1 ? WK : WV);
        dst = Wh + (size_t)wsel * 1024 * 1024;
    }
    int idx = off * 256 + threadIdx.x;
    float4 v = reinterpret_cast<const float4*>(src)[idx];
    ushort4 h;
    h.x = f2h(v.x); h.y = f2h(v.y); h.z = f2h(v.z); h.w = f2h(v.w);
    reinterpret_cast<ushort4*>(dst)[idx] = h;
}

// ============ 256x256 8-phase logits kernel, fp16, K=1024 ============
// S = Qh x Kh'^T (Hamilton perm on Kh cols; sign via pre-negated Khn).
// Multi-component: c = bid>>8 selects perm/sign byte and P_c/pm_c/ps_c slice
// (grid 1024 = all 4 components in one dispatch; grid 256 = single comp).
// Epilogue: wave-local LDS transpose (no barriers), per-64-col stats
// pm/ps[row*64+tcol], coalesced fp16 store of p = exp(S - rowmax_tile).
__global__ __launch_bounds__(512, 2) void logits8(
    const u16* __restrict__ A, const u16* __restrict__ B, const u16* __restrict__ Bneg,
    u16* __restrict__ Pbase, float* __restrict__ pmb, float* __restrict__ psb,
    int perm_all, int sign_all)
{
    constexpr int NT = 16;
    __shared__ u16 L[2][2][256 * 64];
    const int tid = threadIdx.x;
    const int l = tid & 63, w = tid >> 6;
    const int wr = w >> 2, wc = w & 3;
    const int lr = l & 15, lh = l >> 4;
    const int bid = (int)blockIdx.x;
    const int comp = bid >> 8;
    const int perm_packed = (perm_all >> (8 * comp)) & 0xFF;
    const int sign_packed = (sign_all >> (8 * comp)) & 0xFF;
    u16* P = Pbase + (size_t)comp * 4096 * 4096;
    float* pm = pmb + (size_t)comp * 4096 * 64;
    float* ps = psb + (size_t)comp * 4096 * 64;
    const int inner = bid & 255;
    const int xcd = inner & 7, idx = inner >> 3;
    const int rowp = (xcd >> 1) * 4 + (idx >> 3);   // 4-row band per xcd-pair
    const int colp = (xcd & 1) * 8 + (idx & 7);     // 8-col half
    const int row0 = rowp * 256, col0 = colp * 256;
    const int srow = l >> 3;
    const int scol = ((l & 7) ^ (l >> 3)) * 8;

    f32x4 acc[8][4] = {};

    auto stage = [&](int t) {
        int kA = t * 64;
        int ch = kA >> 8;
        int p = (perm_packed >> (2 * ch)) & 3;
        const u16* Bsrc = ((sign_packed >> ch) & 1) ? Bneg : B;
        int kB = (p << 8) + (kA & 255);
        int bf = t & 1;
        #pragma unroll
        for (int i = 0; i < 4; ++i) {
            int r0 = w * 32 + i * 8;
            GLD16(&A[(size_t)(row0 + r0 + srow) * 1024 + kA + scol], &L[bf][0][r0 * 64]);
        }
        #pragma unroll
        for (int i = 0; i < 4; ++i) {
            int r0 = w * 32 + i * 8;
            GLD16(&Bsrc[(size_t)(col0 + r0 + srow) * 1024 + kB + scol], &L[bf][1][r0 * 64]);
        }
    };
    auto readA = [&](int bf, int m, int kh) -> short8 {
        int row = wr * 128 + m * 16 + lr;
        int c = ((kh * 4 + lh) ^ (lr & 7)) * 8;
        return *reinterpret_cast<const short8*>(&L[bf][0][row * 64 + c]);
    };
    auto readB = [&](int bf, int n, int kh) -> short8 {
        int row = wc * 64 + n * 16 + lr;
        int c = ((kh * 4 + lh) ^ (lr & 7)) * 8;
        return *reinterpret_cast<const short8*>(&L[bf][1][row * 64 + c]);
    };

    stage(0);
    stage(1);
    asm volatile("s_waitcnt vmcnt(8)" ::: "memory");
    SBAR();

    #pragma unroll 2
    for (int t = 0; t < NT; ++t) {
        const int bf = t & 1;
        short8 am[4][2], bn[4][2];
        #pragma unroll
        for (int m = 0; m < 4; ++m) { am[m][0] = readA(bf, m, 0); am[m][1] = readA(bf, m, 1); }
        #pragma unroll
        for (int n = 0; n < 2; ++n) { bn[n][0] = readB(bf, n, 0); bn[n][1] = readB(bf, n, 1); }
        SBAR();
        __builtin_amdgcn_s_setprio(1);
        #pragma unroll
        for (int m = 0; m < 4; ++m)
            #pragma unroll
            for (int n = 0; n < 2; ++n) {
                acc[m][n] = MFMA_F16(am[m][0], bn[n][0], acc[m][n]);
                acc[m][n] = MFMA_F16(am[m][1], bn[n][1], acc[m][n]);
            }
        __builtin_amdgcn_s_setprio(0);
        SBAR();
        #pragma unroll
        for (int n = 2; n < 4; ++n) { bn[n][0] = readB(bf, n, 0); bn[n][1] = readB(bf, n, 1); }
        SBAR();
        __builtin_amdgcn_s_setprio(1);
        #pragma unroll
        for (int m = 0; m < 4; ++m)
            #pragma unroll
            for (int n = 2; n < 4; ++n) {
                acc[m][n] = MFMA_F16(am[m][0], bn[n][0], acc[m][n]);
                acc[m][n] = MFMA_F16(am[m][1], bn[n][1], acc[m][n]);
            }
        __builtin_amdgcn_s_setprio(0);
        SBAR();
        #pragma unroll
        for (int m = 0; m < 4; ++m) { am[m][0] = readA(bf, 4 + m, 0); am[m][1] = readA(bf, 4 + m, 1); }
        SBAR();
        __builtin_amdgcn_s_setprio(1);
        #pragma unroll
        for (int m = 0; m < 4; ++m)
            #pragma unroll
            for (int n = 2; n < 4; ++n) {
                acc[4 + m][n] = MFMA_F16(am[m][0], bn[n][0], acc[4 + m][n]);
                acc[4 + m][n] = MFMA_F16(am[m][1], bn[n][1], acc[4 + m][n]);
            }
        __builtin_amdgcn_s_setprio(0);
        SBAR();
        if (t + 2 < NT) stage(t + 2);
        SBAR();
        __builtin_amdgcn_s_setprio(1);
        #pragma unroll
        for (int m = 0; m < 4; ++m)
            #pragma unroll
            for (int n = 0; n < 2; ++n) {
                acc[4 + m][n] = MFMA_F16(am[m][0], bn[n][0], acc[4 + m][n]);
                acc[4 + m][n] = MFMA_F16(am[m][1], bn[n][1], acc[4 + m][n]);
            }
        __builtin_amdgcn_s_setprio(0);
        if (t + 2 < NT) { asm volatile("s_waitcnt vmcnt(8)" ::: "memory"); }
        else           { asm volatile("s_waitcnt vmcnt(0)" ::: "memory"); }
        SBAR();
    }

    // ---- wave-local LDS-transpose epilogue (no cross-wave sync needed) ----
    const int tcol = (col0 >> 6) + wc;
    float* T = reinterpret_cast<float*>(&L[0][0][0]) + w * 1088;   // 16*68 f32
    const int rq = l >> 2;
    const int cq = l & 3;
    #pragma unroll
    for (int m = 0; m < 8; ++m) {
        #pragma unroll
        for (int n = 0; n < 4; ++n)
            #pragma unroll
            for (int j = 0; j < 4; ++j)
                T[(lh * 4 + j) * 68 + n * 16 + lr] = acc[m][n][j];
        float vals[16];
        #pragma unroll
        for (int q = 0; q < 4; ++q) {
            f32x4 v4 = *reinterpret_cast<const f32x4*>(&T[rq * 68 + cq * 16 + q * 4]);
            vals[q * 4 + 0] = v4[0]; vals[q * 4 + 1] = v4[1];
            vals[q * 4 + 2] = v4[2]; vals[q * 4 + 3] = v4[3];
        }
        float mx = vals[0];
        #pragma unroll
        for (int c = 1; c < 16; ++c) mx = fmaxf(mx, vals[c]);
        mx = fmaxf(mx, __shfl_xor(mx, 1, 64));
        mx = fmaxf(mx, __shfl_xor(mx, 2, 64));
        float e[16];
        float s = 0.f;
        #pragma unroll
        for (int c = 0; c < 16; ++c) { e[c] = expf(vals[c] - mx); s += e[c]; }
        s += __shfl_xor(s, 1, 64);
        s += __shfl_xor(s, 2, 64);
        int row = row0 + wr * 128 + m * 16 + rq;
        if (cq == 0) {
            pm[(size_t)row * 64 + tcol] = mx;
            ps[(size_t)row * 64 + tcol] = s;
        }
        ushort8_t d0, d1;
        #pragma unroll
        for (int c = 0; c < 8; ++c) d0[c] = f2h(e[c]);
        #pragma unroll
        for (int c = 0; c < 8; ++c) d1[c] = f2h(e[c + 8]);
        size_t go = (size_t)row * 4096 + col0 + wc * 64 + cq * 16;
        *reinterpret_cast<ushort8_t*>(&P[go]) = d0;
        *reinterpret_cast<ushort8_t*>(&P[go + 8]) = d1;
    }
}

// ============ fused QKV projection, 8-phase 256x256, fp16 K=1024 ============
__global__ __launch_bounds__(512, 2) void qkv8(
    const u16* __restrict__ A, const u16* __restrict__ B,
    u16* __restrict__ Qh, u16* __restrict__ Kh, u16* __restrict__ Khn,
    u16* __restrict__ Vt)
{
    constexpr int NT = 16;
    __shared__ u16 L[2][2][256 * 64];
    const int tid = threadIdx.x;
    const int l = tid & 63, w = tid >> 6;
    const int wr = w >> 2, wc = w & 3;
    const int lr = l & 15, lh = l >> 4;
    const int bid = (int)blockIdx.x;
    const int wgid = (bid & 7) * 24 + (bid >> 3);
    const int row0 = (wgid / 12) * 256, col0 = (wgid % 12) * 256;
    const int srow = l >> 3;
    const int scol = ((l & 7) ^ (l >> 3)) * 8;

    f32x4 acc[8][4] = {};

    auto stage = [&](int t) {
        int k0 = t * 64;
        int bf = t & 1;
        #pragma unroll
        for (int i = 0; i < 4; ++i) {
            int r0 = w * 32 + i * 8;
            GLD16(&A[(size_t)(row0 + r0 + srow) * 1024 + k0 + scol], &L[bf][0][r0 * 64]);
        }
        #pragma unroll
        for (int i = 0; i < 4; ++i) {
            int r0 = w * 32 + i * 8;
            GLD16(&B[(size_t)(col0 + r0 + srow) * 1024 + k0 + scol], &L[bf][1][r0 * 64]);
        }
    };
    auto readA = [&](int bf, int m, int kh) -> short8 {
        int row = wr * 128 + m * 16 + lr;
        int c = ((kh * 4 + lh) ^ (lr & 7)) * 8;
        return *reinterpret_cast<const short8*>(&L[bf][0][row * 64 + c]);
    };
    auto readB = [&](int bf, int n, int kh) -> short8 {
        int row = wc * 64 + n * 16 + lr;
        int c = ((kh * 4 + lh) ^ (lr & 7)) * 8;
        return *reinterpret_cast<const short8*>(&L[bf][1][row * 64 + c]);
    };

    stage(0);
    stage(1);
    asm volatile("s_waitcnt vmcnt(8)" ::: "memory");
    SBAR();

    #pragma unroll 2
    for (int t = 0; t < NT; ++t) {
        const int bf = t & 1;
        short8 am[4][2], bn[4][2];
        #pragma unroll
        for (int m = 0; m < 4; ++m) { am[m][0] = readA(bf, m, 0); am[m][1] = readA(bf, m, 1); }
        #pragma unroll
        for (int n = 0; n < 2; ++n) { bn[n][0] = readB(bf, n, 0); bn[n][1] = readB(bf, n, 1); }
        SBAR();
        __builtin_amdgcn_s_setprio(1);
        #pragma unroll
        for (int m = 0; m < 4; ++m)
            #pragma unroll
            for (int n = 0; n < 2; ++n) {
                acc[m][n] = MFMA_F16(am[m][0], bn[n][0], acc[m][n]);
                acc[m][n] = MFMA_F16(am[m][1], bn[n][1], acc[m][n]);
            }
        __builtin_amdgcn_s_setprio(0);
        SBAR();
        #pragma unroll
        for (int n = 2; n < 4; ++n) { bn[n][0] = readB(bf, n, 0); bn[n][1] = readB(bf, n, 1); }
        SBAR();
        __builtin_amdgcn_s_setprio(1);
        #pragma unroll
        for (int m = 0; m < 4; ++m)
            #pragma unroll
            for (int n = 2; n < 4; ++n) {
                acc[m][n] = MFMA_F16(am[m][0], bn[n][0], acc[m][n]);
                acc[m][n] = MFMA_F16(am[m][1], bn[n][1], acc[m][n]);
            }
        __builtin_amdgcn_s_setprio(0);
        SBAR();
        #pragma unroll
        for (int m = 0; m < 4; ++m) { am[m][0] = readA(bf, 4 + m, 0); am[m][1] = readA(bf, 4 + m, 1); }
        SBAR();
        __builtin_amdgcn_s_setprio(1);
        #pragma unroll
        for (int m = 0; m < 4; ++m)
            #pragma unroll
            for (int n = 2; n < 4; ++n) {
                acc[4 + m][n] = MFMA_F16(am[m][0], bn[n][0], acc[4 + m][n]);
                acc[4 + m][n] = MFMA_F16(am[m][1], bn[n][1], acc[4 + m][n]);
            }
        __builtin_amdgcn_s_setprio(0);
        SBAR();
        if (t + 2 < NT) stage(t + 2);
        SBAR();
        __builtin_amdgcn_s_setprio(1);
        #pragma unroll
        for (int m = 0; m < 4; ++m)
            #pragma unroll
            for (int n = 0; n < 2; ++n) {
                acc[4 + m][n] = MFMA_F16(am[m][0], bn[n][0], acc[4 + m][n]);
                acc[4 + m][n] = MFMA_F16(am[m][1], bn[n][1], acc[4 + m][n]);
            }
        __builtin_amdgcn_s_setprio(0);
        if (t + 2 < NT) { asm volatile("s_waitcnt vmcnt(8)" ::: "memory"); }
        else           { asm volatile("s_waitcnt vmcnt(0)" ::: "memory"); }
        SBAR();
    }

    const int mode = col0 >> 10;   // 0=Q, 1=K, 2=V (uniform per block)
    #pragma unroll
    for (int m = 0; m < 8; ++m)
        #pragma unroll
        for (int n = 0; n < 4; ++n) {
            int gr = row0 + wr * 128 + m * 16 + lh * 4;
            int gc = col0 + wc * 64 + n * 16 + lr;
            int gcl = gc & 1023;
            f32x4 v = acc[m][n];
            if (mode == 0) {
                #pragma unroll
                for (int j = 0; j < 4; ++j)
                    Qh[(size_t)(gr + j) * 1024 + gcl] = f2h(v[j]);
            } else if (mode == 1) {
                #pragma unroll
                for (int j = 0; j < 4; ++j) {
                    u16 h = f2h(v[j]);
                    size_t o = (size_t)(gr + j) * 1024 + gcl;
                    Kh[o] = h; Khn[o] = h ^ 0x8000;
                }
            } else {
                ushort4 o;
                o.x = f2h(v[0]); o.y = f2h(v[1]); o.z = f2h(v[2]); o.w = f2h(v[3]);
                *reinterpret_cast<ushort4*>(&Vt[(size_t)gcl * 4096 + gr]) = o;
            }
        }
}

// ============ fused softmax + PV, split-K 8, fp16 p input ============
template<bool WRITE_W>
__global__ __launch_bounds__(256) void pv_fused(
    const u16* __restrict__ P, float* __restrict__ Wout,
    const u16* __restrict__ Vt, const float* __restrict__ pm,
    const float* __restrict__ ps, u16* __restrict__ ypart, int c256)
{
    __shared__ u16 As[64 * 64];
    __shared__ u16 Bs[256 * 64];
    __shared__ float Red[64][4];
    __shared__ float Ms[64], Is[64];
    const int tid = threadIdx.x;
    const int l = tid & 63, w = tid >> 6;
    const int lr = l & 15, lh = l >> 4;
    const int kc = blockIdx.x;
    const int row0 = blockIdx.y * 64;
    const int kbase = kc * 512;
    const int srow = l >> 3, scol = ((l & 7) ^ (l >> 3)) * 8;

    {
        int row = tid & 63, part = tid >> 6;
        const float* pmr = &pm[(size_t)(row0 + row) * 64 + part * 16];
        const float* psr = &ps[(size_t)(row0 + row) * 64 + part * 16];
        float M = -INFINITY;
        #pragma unroll
        for (int i = 0; i < 16; ++i) M = fmaxf(M, pmr[i]);
        Red[row][part] = M;
        __syncthreads();
        float Mg = fmaxf(fmaxf(Red[row][0], Red[row][1]),
                         fmaxf(Red[row][2], Red[row][3]));
        float S = 0.f;
        #pragma unroll
        for (int i = 0; i < 16; ++i) S += psr[i] * expf(pmr[i] - Mg);
        __syncthreads();
        Red[row][part] = S;
        __syncthreads();
        if (tid < 64) {
            float Sg = Red[tid][0] + Red[tid][1] + Red[tid][2] + Red[tid][3];
            Ms[tid] = Mg;
            Is[tid] = 1.0f / Sg;
        }
        __syncthreads();
    }

    float Mr[4], Ir[4];
    #pragma unroll
    for (int i = 0; i < 4; ++i) { int r = (tid >> 4) + i * 16; Mr[i] = Ms[r]; Ir[i] = Is[r]; }

    f32x4 acc[4][4] = {};

    for (int kt = 0; kt < 8; ++kt) {
        const int tcol = kc * 8 + kt;
        __syncthreads();
        // stage A: w = p * alpha -> fp16, XOR-swizzled write
        #pragma unroll
        for (int i = 0; i < 4; ++i) {
            int idx = tid + i * 256;
            int r = idx >> 4, s4 = idx & 15;
            float alpha = expf(pm[(size_t)(row0 + r) * 64 + tcol] - Mr[i]) * Ir[i];
            size_t ga = (size_t)(row0 + r) * 4096 + kbase + kt * 64 + s4 * 4;
            ushort4 dv = *reinterpret_cast<const ushort4*>(&P[ga]);
            float e0 = h2f(dv.x) * alpha;
            float e1 = h2f(dv.y) * alpha;
            float e2 = h2f(dv.z) * alpha;
            float e3 = h2f(dv.w) * alpha;
            if (WRITE_W)
                *reinterpret_cast<float4*>(&Wout[ga]) = make_float4(e0, e1, e2, e3);
            ushort4 h;
            h.x = f2h(e0); h.y = f2h(e1); h.z = f2h(e2); h.w = f2h(e3);
            int dst = ((s4 >> 1) ^ (r & 7)) * 8 + (s4 & 1) * 4;
            *reinterpret_cast<ushort4*>(&As[r * 64 + dst]) = h;
        }
        #pragma unroll
        for (int i = 0; i < 8; ++i) {
            int r0 = w * 64 + i * 8;
            GLD16(&Vt[(size_t)(c256 + r0 + srow) * 4096 + kbase + kt * 64 + scol],
                  &Bs[r0 * 64]);
        }
        __syncthreads();
        #pragma unroll
        for (int kh = 0; kh < 2; ++kh) {
            short8 af[4], bfv[4];
            #pragma unroll
            for (int m = 0; m < 4; ++m)
                af[m] = *reinterpret_cast<const short8*>(
                    &As[(m * 16 + lr) * 64 + ((kh * 4 + lh) ^ (lr & 7)) * 8]);
            #pragma unroll
            for (int n = 0; n < 4; ++n)
                bfv[n] = *reinterpret_cast<const short8*>(
                    &Bs[(w * 64 + n * 16 + lr) * 64 + ((kh * 4 + lh) ^ (lr & 7)) * 8]);
            #pragma unroll
            for (int m = 0; m < 4; ++m)
                #pragma unroll
                for (int n = 0; n < 4; ++n)
                    acc[m][n] = MFMA_F16(af[m], bfv[n], acc[m][n]);
        }
    }

    #pragma unroll
    for (int m = 0; m < 4; ++m)
        #pragma unroll
        for (int n = 0; n < 4; ++n) {
            int rr = m * 16 + lh * 4;
            int col = w * 64 + n * 16 + lr;
            #pragma unroll
            for (int j = 0; j < 4; ++j)
                ypart[((size_t)kc * 4096 + row0 + rr + j) * 256 + col] = f2h(acc[m][n][j]);
        }
}

// y[:, c256..c256+256] = sum over 8 k-chunk fp16 partials (f32 accumulate)
__global__ __launch_bounds__(256) void reduce_y(const u16* __restrict__ ypart,
                                                float* __restrict__ y, int c256)
{
    int idx = blockIdx.x * 256 + threadIdx.x;
    int r = idx >> 6, c4 = (idx & 63) * 4;
    float s0 = 0.f, s1 = 0.f, s2 = 0.f, s3 = 0.f;
    #pragma unroll
    for (int kc = 0; kc < 8; ++kc) {
        ushort4 p = *reinterpret_cast<const ushort4*>(
            &ypart[((size_t)kc * 4096 + r) * 256 + c4]);
        s0 += h2f(p.x); s1 += h2f(p.y); s2 += h2f(p.z); s3 += h2f(p.w);
    }
    *reinterpret_cast<float4*>(&y[(size_t)r * 1024 + c256 + c4]) =
        make_float4(s0, s1, s2, s3);
}

extern "C" void kernel_launch(void* const* d_in, const int* in_sizes, int n_in,
                              void* d_out, int out_size, void* d_ws, size_t ws_size,
                              hipStream_t stream)
{
    const int n = 4096, d = 1024;
    const size_t NN = (size_t)n * n;
    const float* x  = (const float*)d_in[0];
    const float* WQ = (const float*)d_in[1];
    const float* WK = (const float*)d_in[2];
    const float* WV = (const float*)d_in[3];

    float* y = (float*)d_out;                  // [4096,1024]
    float* wout = y + (size_t)n * d;           // [4096,4096] final w (c=3 only)

    const int permv[4] = {0xE4, 0xB1, 0x4E, 0x1B};
    const int signv[4] = {0x0E, 0x08, 0x02, 0x04};
    const int PERM_ALL = 0x1B4EB1E4;
    const int SIGN_ALL = 0x0402080E;

    // mega layout: P4 [4][4096][4096] fp16 + aux. xh/Wh alias P4 head
    // (consumed by qkv8 before logits writes P — stream-ordered).
    const size_t need_mega =
        (4 * NN + 4 * (size_t)n * d + (size_t)8 * n * 256) * 2 +
        2 * 4 * (size_t)n * 64 * 4;

    if (ws_size >= need_mega) {
        u16* P4   = (u16*)d_ws;                    // 134.2 MB
        u16* xh   = P4;                            // alias
        u16* Wh   = P4 + (size_t)n * 1024;         // alias
        u16* Qh   = P4 + 4 * NN;
        u16* Kh   = Qh + (size_t)n * 1024;
        u16* Khn  = Kh + (size_t)n * 1024;
        u16* Vt   = Khn + (size_t)n * 1024;
        u16* ypart = Vt + (size_t)d * 4096;
        float* pm4 = (float*)(ypart + (size_t)8 * n * 256);  // [4][4096][64]
        float* ps4 = pm4 + 4 * (size_t)n * 64;

        to_h_all<<<7168, 256, 0, stream>>>(x, WQ, WK, WV, xh, Wh);
        qkv8<<<192, 512, 0, stream>>>(xh, Wh, Qh, Kh, Khn, Vt);
        // all 4 components in ONE dispatch (4 rounds pipeline on HW)
        logits8<<<1024, 512, 0, stream>>>(Qh, Kh, Khn, P4, pm4, ps4,
                                          PERM_ALL, SIGN_ALL);
        for (int c = 0; c < 4; ++c) {
            const u16* Pc = P4 + (size_t)c * NN;
            const float* pmc = pm4 + (size_t)c * n * 64;
            const float* psc = ps4 + (size_t)c * n * 64;
            if (c == 3)
                pv_fused<true><<<dim3(8, 64), 256, 0, stream>>>(
                    Pc, wout, Vt, pmc, psc, ypart, c * 256);
            else
                pv_fused<false><<<dim3(8, 64), 256, 0, stream>>>(
                    Pc, wout, Vt, pmc, psc, ypart, c * 256);
            reduce_y<<<1024, 256, 0, stream>>>(ypart, y, c * 256);
        }
    } else {
        // fallback: R13 sequence (single-comp logits, P reused per comp)
        u16* P    = (u16*)d_ws;                    // [4096][4096] fp16
        u16* xh   = P;                             // alias
        u16* Wh   = P + (size_t)n * 1024;          // alias
        u16* Qh   = P + NN;
        u16* Kh   = Qh + (size_t)n * 1024;
        u16* Khn  = Kh + (size_t)n * 1024;
        u16* Vt   = Khn + (size_t)n * 1024;
        u16* ypart = Vt + (size_t)d * 4096;
        float* pm = (float*)(ypart + (size_t)8 * n * 256);
        float* ps = pm + (size_t)n * 64;

        to_h_all<<<7168, 256, 0, stream>>>(x, WQ, WK, WV, xh, Wh);
        qkv8<<<192, 512, 0, stream>>>(xh, Wh, Qh, Kh, Khn, Vt);
        for (int c = 0; c < 4; ++c) {
            logits8<<<256, 512, 0, stream>>>(Qh, Kh, Khn, P, pm, ps,
                                             permv[c], signv[c]);
            if (c == 3)
                pv_fused<true><<<dim3(8, 64), 256, 0, stream>>>(
                    P, wout, Vt, pm, ps, ypart, c * 256);
            else
                pv_fused<false><<<dim3(8, 64), 256, 0, stream>>>(
                    P, wout, Vt, pm, ps, ypart, c * 256);
            reduce_y<<<1024, 256, 0, stream>>>(ypart, y, c * 256);
        }
    }
}